// Round 13
// baseline (72.265 us; speedup 1.0000x reference)
//
#include <hip/hip_runtime.h>

#define IMG 28
#define FLATK 784     // 28*28
#define OHW 26
#define FLAT 676      // 26*26
#define HID 100
#define NCLS 10
#define KP 800        // K padded to 25*32
#define BM 128        // rows per block (4 row-slabs x 32 rows)

typedef __attribute__((ext_vector_type(8))) short bfrag;   // 8 bf16 (4 VGPR)
typedef __attribute__((ext_vector_type(4))) float f32x4;
typedef __attribute__((ext_vector_type(4))) unsigned int u32x4;

__device__ __forceinline__ unsigned short f2bf(float f) {
    unsigned u = __float_as_uint(f);
    u = (u + 0x7fffu + ((u >> 16) & 1u)) >> 16;   // RNE
    return (unsigned short)u;
}

// Kernel 1: fold conv into fc1 -> bf16 W1eff [128 n][800 k] (zero-padded),
// and w2 -> bf16 [16 n][128 k] (zero-padded).
__global__ void build_weights(const float* __restrict__ conv_w,
                              const float* __restrict__ w1,
                              const float* __restrict__ w2,
                              unsigned short* __restrict__ w1b,
                              unsigned short* __restrict__ w2b) {
    int idx = blockIdx.x * blockDim.x + threadIdx.x;
    if (idx < 128 * KP) {
        int n = idx / KP, k = idx - n * KP;
        float val = 0.f;
        if (n < HID && k < FLATK) {
            int qr = k / IMG, qc = k % IMG;
            #pragma unroll
            for (int i = 0; i < 3; ++i) {
                int r = qr - i;
                if (r < 0 || r >= OHW) continue;
                #pragma unroll
                for (int j = 0; j < 3; ++j) {
                    int c = qc - j;
                    if (c < 0 || c >= OHW) continue;
                    val += conv_w[i * 3 + j] * w1[n * FLAT + r * OHW + c];
                }
            }
        }
        w1b[idx] = f2bf(val);
    } else {
        int t = idx - 128 * KP;
        if (t < 16 * 128) {
            int n = t >> 7, k = t & 127;
            float v = (n < NCLS && k < HID) ? w2[n * HID + k] : 0.f;
            w2b[t] = f2bf(v);
        }
    }
}

// load step S's A-fragments (both mf rows) into pre[PH]; PH,S literal ->
// SROA-promotes to registers (no scratch).
#define LOADA(PH, S) do {                                                      \
    int k_ = (S) * 32 + (khi << 3);                                            \
    if (k_ >= FLATK) k_ -= FLATK;  /* S=24 pad lanes: in-row garbage, B=0 */   \
    pre[PH][0] = *(const f32x4*)(xr0 + k_);                                    \
    pre[PH][1] = *(const f32x4*)(xr0 + k_ + 4);                                \
    pre[PH][2] = *(const f32x4*)(xr1 + k_);                                    \
    pre[PH][3] = *(const f32x4*)(xr1 + k_ + 4);                                \
} while (0)

// consume step S from pre[PH]: cvt_pk -> 2 A-fragments; 4 inline B-loads
// (this wave's 64-col half); 8 MFMA.
#define COMP(PH, S) do {                                                       \
    union { u32x4 u; bfrag b; } a0_, a1_;                                      \
    asm("v_cvt_pk_bf16_f32 %0, %1, %2" : "=v"(a0_.u.x) : "v"(pre[PH][0].x), "v"(pre[PH][0].y)); \
    asm("v_cvt_pk_bf16_f32 %0, %1, %2" : "=v"(a0_.u.y) : "v"(pre[PH][0].z), "v"(pre[PH][0].w)); \
    asm("v_cvt_pk_bf16_f32 %0, %1, %2" : "=v"(a0_.u.z) : "v"(pre[PH][1].x), "v"(pre[PH][1].y)); \
    asm("v_cvt_pk_bf16_f32 %0, %1, %2" : "=v"(a0_.u.w) : "v"(pre[PH][1].z), "v"(pre[PH][1].w)); \
    asm("v_cvt_pk_bf16_f32 %0, %1, %2" : "=v"(a1_.u.x) : "v"(pre[PH][2].x), "v"(pre[PH][2].y)); \
    asm("v_cvt_pk_bf16_f32 %0, %1, %2" : "=v"(a1_.u.y) : "v"(pre[PH][2].z), "v"(pre[PH][2].w)); \
    asm("v_cvt_pk_bf16_f32 %0, %1, %2" : "=v"(a1_.u.z) : "v"(pre[PH][3].x), "v"(pre[PH][3].y)); \
    asm("v_cvt_pk_bf16_f32 %0, %1, %2" : "=v"(a1_.u.w) : "v"(pre[PH][3].z), "v"(pre[PH][3].w)); \
    _Pragma("unroll")                                                          \
    for (int nt = 0; nt < 4; ++nt) {                                           \
        const bfrag bw = *(const bfrag*)(w1b + (size_t)(ncol0 + (nt << 4) + r15) * KP \
                                         + (S) * 32 + (khi << 3));             \
        acc0[nt] = __builtin_amdgcn_mfma_f32_16x16x32_bf16(a0_.b, bw, acc0[nt], 0, 0, 0); \
        acc1[nt] = __builtin_amdgcn_mfma_f32_16x16x32_bf16(a1_.b, bw, acc1[nt], 0, 0, 0); \
    }                                                                          \
} while (0)

// Kernel 2: barrier-free main loop, 8 waves (4 row-slabs x 2 col-halves).
// Wave (wvm,wvn): rows wvm*32..+32, cols wvn*64..+64. 2x wave-level memory
// concurrency vs R11 at identical HBM/L2 traffic (x re-read hits L1/L2;
// B-frags per CU unchanged). VGPR target <=128 -> 16 waves/CU.
__global__ __launch_bounds__(512, 4) void fused_fwd(
    const float* __restrict__ x,              // [65536][784] f32
    const unsigned short* __restrict__ w1b,   // [128][800] bf16
    const float* __restrict__ b1,             // [100]
    const unsigned short* __restrict__ w2b,   // [16][128] bf16
    const float* __restrict__ b2,             // [10]
    float* __restrict__ out)                  // [65536][10] f32
{
    __shared__ unsigned short H1[BM][136];    // 34816 B, epilogue only

    const int tid  = threadIdx.x;
    const int lane = tid & 63;
    const int wv   = tid >> 6;       // 0..7
    const int wvm  = wv & 3;         // row slab (32 rows)
    const int wvn  = wv >> 2;        // col half (64 cols)
    const int r15  = lane & 15;
    const int khi  = lane >> 4;      // 0..3 (k-slice *8)
    const int row0 = blockIdx.x * BM;
    const int ncol0 = wvn << 6;      // 0 or 64

    // A rows: lane holds row r15 of mf0 slab and row 16+r15 of mf1 slab
    const float* xr0 = x + (size_t)(row0 + (wvm << 5) + r15) * FLATK;
    const float* xr1 = xr0 + 16 * FLATK;

    f32x4 acc0[4], acc1[4];
    #pragma unroll
    for (int n = 0; n < 4; ++n) {
        acc0[n] = f32x4{0.f, 0.f, 0.f, 0.f};
        acc1[n] = f32x4{0.f, 0.f, 0.f, 0.f};
    }

    f32x4 pre[3][4];   // depth-3 A ring (literal indices only)

    LOADA(0, 0); LOADA(1, 1); LOADA(2, 2);

    COMP(0, 0);  LOADA(0, 3);   COMP(1, 1);  LOADA(1, 4);   COMP(2, 2);  LOADA(2, 5);
    COMP(0, 3);  LOADA(0, 6);   COMP(1, 4);  LOADA(1, 7);   COMP(2, 5);  LOADA(2, 8);
    COMP(0, 6);  LOADA(0, 9);   COMP(1, 7);  LOADA(1, 10);  COMP(2, 8);  LOADA(2, 11);
    COMP(0, 9);  LOADA(0, 12);  COMP(1, 10); LOADA(1, 13);  COMP(2, 11); LOADA(2, 14);
    COMP(0, 12); LOADA(0, 15);  COMP(1, 13); LOADA(1, 16);  COMP(2, 14); LOADA(2, 17);
    COMP(0, 15); LOADA(0, 18);  COMP(1, 16); LOADA(1, 19);  COMP(2, 17); LOADA(2, 20);
    COMP(0, 18); LOADA(0, 21);  COMP(1, 19); LOADA(1, 22);  COMP(2, 20); LOADA(2, 23);
    COMP(0, 21); LOADA(0, 24);  COMP(1, 22);                COMP(2, 23);
    COMP(0, 24);

    // epilogue 1: bias + relu -> bf16 h1 in LDS [128][136] (col halves disjoint)
    #pragma unroll
    for (int nt = 0; nt < 4; ++nt) {
        int col = ncol0 + (nt << 4) + r15;
        float bias = (col < HID) ? b1[col] : 0.f;
        int rb0 = (wvm << 5) + (khi << 2);
        #pragma unroll
        for (int q = 0; q < 4; ++q) {
            float v0 = acc0[nt][q] + bias;
            float v1 = acc1[nt][q] + bias;
            H1[rb0 + q][col]      = f2bf(fmaxf(v0, 0.f));
            H1[rb0 + 16 + q][col] = f2bf(fmaxf(v1, 0.f));
        }
    }
    __syncthreads();

    // layer 2: 8 waves x 16 rows each over K=128 (pad cols/k are exact zeros)
    f32x4 acc2 = f32x4{0.f, 0.f, 0.f, 0.f};
    const int r2 = (wv << 4) + r15;
    #pragma unroll
    for (int ks = 0; ks < 4; ++ks) {
        const bfrag bwv = *(const bfrag*)(w2b + r15 * 128 + (ks << 5) + (khi << 3));
        const bfrag ah = *(const bfrag*)&H1[r2][(ks << 5) + (khi << 3)];
        acc2 = __builtin_amdgcn_mfma_f32_16x16x32_bf16(ah, bwv, acc2, 0, 0, 0);
    }

    if (r15 < NCLS) {
        float bias2 = b2[r15];
        int rbase = row0 + (wv << 4) + (khi << 2);
        #pragma unroll
        for (int q = 0; q < 4; ++q)
            out[(size_t)(rbase + q) * NCLS + r15] = acc2[q] + bias2;
    }
}

extern "C" void kernel_launch(void* const* d_in, const int* in_sizes, int n_in,
                              void* d_out, int out_size, void* d_ws, size_t ws_size,
                              hipStream_t stream) {
    const float* x      = (const float*)d_in[0];
    const float* conv_w = (const float*)d_in[1];
    const float* w1     = (const float*)d_in[2];
    const float* b1     = (const float*)d_in[3];
    const float* w2     = (const float*)d_in[4];
    const float* b2     = (const float*)d_in[5];
    float* out = (float*)d_out;

    unsigned short* w1b = (unsigned short*)d_ws;   // 128*800*2 = 204.8 KB
    unsigned short* w2b = w1b + 128 * KP;          // 16*128*2  = 4 KB

    build_weights<<<(128 * KP + 16 * 128 + 255) / 256, 256, 0, stream>>>(conv_w, w1, w2, w1b, w2b);
    fused_fwd<<<65536 / BM, 512, 0, stream>>>(x, w1b, b1, w2b, b2, out);
}

// Round 14
// 48.146 us; speedup vs baseline: 1.5010x; 1.5010x over previous
//
#include <hip/hip_runtime.h>

#define IMG 28
#define FLATK 784     // 28*28
#define OHW 26
#define FLAT 676      // 26*26
#define HID 100
#define NCLS 10
#define KP 800        // K padded to 25*32
#define BM 256        // rows per block (8 waves x 32 rows, mf=2)
#define BSTRIDE 808   // LDS B row stride in bf16 (800 + 8 pad)

typedef __attribute__((ext_vector_type(8))) short bfrag;   // 8 bf16 (4 VGPR)
typedef __attribute__((ext_vector_type(4))) float f32x4;
typedef __attribute__((ext_vector_type(4))) unsigned int u32x4;

__device__ __forceinline__ unsigned short f2bf(float f) {
    unsigned u = __float_as_uint(f);
    u = (u + 0x7fffu + ((u >> 16) & 1u)) >> 16;   // RNE
    return (unsigned short)u;
}

// Kernel 1: fold conv into fc1 -> bf16 W1eff [128 n][800 k] (zero-padded),
// and w2 -> bf16 [16 n][128 k] (zero-padded).
__global__ void build_weights(const float* __restrict__ conv_w,
                              const float* __restrict__ w1,
                              const float* __restrict__ w2,
                              unsigned short* __restrict__ w1b,
                              unsigned short* __restrict__ w2b) {
    int idx = blockIdx.x * blockDim.x + threadIdx.x;
    if (idx < 128 * KP) {
        int n = idx / KP, k = idx - n * KP;
        float val = 0.f;
        if (n < HID && k < FLATK) {
            int qr = k / IMG, qc = k % IMG;
            #pragma unroll
            for (int i = 0; i < 3; ++i) {
                int r = qr - i;
                if (r < 0 || r >= OHW) continue;
                #pragma unroll
                for (int j = 0; j < 3; ++j) {
                    int c = qc - j;
                    if (c < 0 || c >= OHW) continue;
                    val += conv_w[i * 3 + j] * w1[n * FLAT + r * OHW + c];
                }
            }
        }
        w1b[idx] = f2bf(val);
    } else {
        int t = idx - 128 * KP;
        if (t < 16 * 128) {
            int n = t >> 7, k = t & 127;
            float v = (n < NCLS && k < HID) ? w2[n * HID + k] : 0.f;
            w2b[t] = f2bf(v);
        }
    }
}

// load step S's A-fragments (both mf rows) into pre[PH]; PH,S literal ->
// SROA-promotes to registers (no scratch).
#define LOADA(PH, S) do {                                                      \
    int k_ = (S) * 32 + (khi << 3);                                            \
    if (k_ >= FLATK) k_ -= FLATK;  /* S=24 pad lanes: in-row garbage, B=0 */   \
    pre[PH][0] = *(const f32x4*)(xr0 + k_);                                    \
    pre[PH][1] = *(const f32x4*)(xr0 + k_ + 4);                                \
    pre[PH][2] = *(const f32x4*)(xr1 + k_);                                    \
    pre[PH][3] = *(const f32x4*)(xr1 + k_ + 4);                                \
} while (0)

// consume step S from pre[PH]: cvt_pk -> 2 A-fragments; 7 B ds_reads from
// LDS (lgkmcnt queue -- MFMA waits no longer drain the A vmcnt queue);
// 14 MFMA. Tile 6 overlaps cols 84..99 (avoids OOB LDS rows 100+).
#define COMP(PH, S) do {                                                       \
    union { u32x4 u; bfrag b; } a0_, a1_;                                      \
    asm("v_cvt_pk_bf16_f32 %0, %1, %2" : "=v"(a0_.u.x) : "v"(pre[PH][0].x), "v"(pre[PH][0].y)); \
    asm("v_cvt_pk_bf16_f32 %0, %1, %2" : "=v"(a0_.u.y) : "v"(pre[PH][0].z), "v"(pre[PH][0].w)); \
    asm("v_cvt_pk_bf16_f32 %0, %1, %2" : "=v"(a0_.u.z) : "v"(pre[PH][1].x), "v"(pre[PH][1].y)); \
    asm("v_cvt_pk_bf16_f32 %0, %1, %2" : "=v"(a0_.u.w) : "v"(pre[PH][1].z), "v"(pre[PH][1].w)); \
    asm("v_cvt_pk_bf16_f32 %0, %1, %2" : "=v"(a1_.u.x) : "v"(pre[PH][2].x), "v"(pre[PH][2].y)); \
    asm("v_cvt_pk_bf16_f32 %0, %1, %2" : "=v"(a1_.u.y) : "v"(pre[PH][2].z), "v"(pre[PH][2].w)); \
    asm("v_cvt_pk_bf16_f32 %0, %1, %2" : "=v"(a1_.u.z) : "v"(pre[PH][3].x), "v"(pre[PH][3].y)); \
    asm("v_cvt_pk_bf16_f32 %0, %1, %2" : "=v"(a1_.u.w) : "v"(pre[PH][3].z), "v"(pre[PH][3].w)); \
    _Pragma("unroll")                                                          \
    for (int nt = 0; nt < 7; ++nt) {                                           \
        int n_ = (nt < 6) ? ((nt << 4) + r15) : (84 + r15);                    \
        const bfrag bw = *(const bfrag*)(Blds + (size_t)n_ * BSTRIDE           \
                                         + (S) * 32 + (khi << 3));             \
        acc0[nt] = __builtin_amdgcn_mfma_f32_16x16x32_bf16(a0_.b, bw, acc0[nt], 0, 0, 0); \
        acc1[nt] = __builtin_amdgcn_mfma_f32_16x16x32_bf16(a1_.b, bw, acc1[nt], 0, 0, 0); \
    }                                                                          \
} while (0)

// Kernel 2: B fully resident in LDS (staged once per block); A global->reg
// depth-3 ring, barrier-free main loop. 8 waves x 32 rows (BM=256, grid=256
// = 1 block/CU). LDS aliased: B (161.6 KB) in main loop, H1 (69.6 KB) after.
__global__ __launch_bounds__(512) void fused_fwd(
    const float* __restrict__ x,              // [65536][784] f32
    const unsigned short* __restrict__ w1b,   // [128][800] bf16
    const float* __restrict__ b1,             // [100]
    const unsigned short* __restrict__ w2b,   // [16][128] bf16
    const float* __restrict__ b2,             // [10]
    float* __restrict__ out)                  // [65536][10] f32
{
    __shared__ char smem[100 * BSTRIDE * 2] __attribute__((aligned(128)));  // 161600 B
    unsigned short* Blds = (unsigned short*)smem;

    const int tid  = threadIdx.x;
    const int lane = tid & 63;
    const int wv   = tid >> 6;       // 0..7
    const int r15  = lane & 15;
    const int khi  = lane >> 4;      // 0..3 (k-slice *8)
    const int row0 = blockIdx.x * BM;

    // stage B: w1b rows 0..99 (incl. zero k-pad 784..799) -> LDS, 16B units
    for (int i = tid; i < 100 * 100; i += 512) {
        int n = i / 100, kv = i - n * 100;
        *(bfrag*)(Blds + (size_t)n * BSTRIDE + (kv << 3)) =
            *(const bfrag*)(w1b + (size_t)n * KP + (kv << 3));
    }
    __syncthreads();

    // A rows: lane holds row r15 of mf0 slab and row 16+r15 of mf1 slab
    const float* xr0 = x + (size_t)(row0 + (wv << 5) + r15) * FLATK;
    const float* xr1 = xr0 + 16 * FLATK;

    f32x4 acc0[7], acc1[7];
    #pragma unroll
    for (int n = 0; n < 7; ++n) {
        acc0[n] = f32x4{0.f, 0.f, 0.f, 0.f};
        acc1[n] = f32x4{0.f, 0.f, 0.f, 0.f};
    }

    f32x4 pre[3][4];   // depth-3 A ring (literal indices only)

    LOADA(0, 0); LOADA(1, 1); LOADA(2, 2);

    COMP(0, 0);  LOADA(0, 3);   COMP(1, 1);  LOADA(1, 4);   COMP(2, 2);  LOADA(2, 5);
    COMP(0, 3);  LOADA(0, 6);   COMP(1, 4);  LOADA(1, 7);   COMP(2, 5);  LOADA(2, 8);
    COMP(0, 6);  LOADA(0, 9);   COMP(1, 7);  LOADA(1, 10);  COMP(2, 8);  LOADA(2, 11);
    COMP(0, 9);  LOADA(0, 12);  COMP(1, 10); LOADA(1, 13);  COMP(2, 11); LOADA(2, 14);
    COMP(0, 12); LOADA(0, 15);  COMP(1, 13); LOADA(1, 16);  COMP(2, 14); LOADA(2, 17);
    COMP(0, 15); LOADA(0, 18);  COMP(1, 16); LOADA(1, 19);  COMP(2, 17); LOADA(2, 20);
    COMP(0, 18); LOADA(0, 21);  COMP(1, 19); LOADA(1, 22);  COMP(2, 20); LOADA(2, 23);
    COMP(0, 21); LOADA(0, 24);  COMP(1, 22);                COMP(2, 23);
    COMP(0, 24);

    __syncthreads();   // B-LDS dead; alias H1 over it

    // epilogue 1: bias+relu -> bf16 h1 [256][136]; zero cols 100..127 (layer-2
    // k-range); nt0-5 write cols 0..95, nt6 writes cols 96..99 -- all disjoint.
    unsigned short (*H1)[136] = (unsigned short (*)[136])smem;
    for (int i = tid; i < 256 * 28; i += 512) {
        int r = i / 28, c = 100 + (i - (i / 28) * 28);
        H1[r][c] = 0;
    }
    #pragma unroll
    for (int nt = 0; nt < 7; ++nt) {
        int col = (nt < 6) ? ((nt << 4) + r15) : (84 + r15);
        bool wr = (nt < 6) || (col >= 96);
        float bias = (col < HID) ? b1[col] : 0.f;
        int rb0 = (wv << 5) + (khi << 2);
        if (wr) {
            #pragma unroll
            for (int q = 0; q < 4; ++q) {
                float v0 = acc0[nt][q] + bias;
                float v1 = acc1[nt][q] + bias;
                H1[rb0 + q][col]      = f2bf(fmaxf(v0, 0.f));
                H1[rb0 + 16 + q][col] = f2bf(fmaxf(v1, 0.f));
            }
        }
    }
    __syncthreads();

    // layer 2: 8 waves x 32 rows (mf=2) over K=128 (pads are exact zeros)
    f32x4 acc2[2] = {f32x4{0.f,0.f,0.f,0.f}, f32x4{0.f,0.f,0.f,0.f}};
    #pragma unroll
    for (int ks = 0; ks < 4; ++ks) {
        const bfrag bwv = *(const bfrag*)(w2b + r15 * 128 + (ks << 5) + (khi << 3));
        #pragma unroll
        for (int mf = 0; mf < 2; ++mf) {
            int r = (wv << 5) + (mf << 4) + r15;
            const bfrag ah = *(const bfrag*)&H1[r][(ks << 5) + (khi << 3)];
            acc2[mf] = __builtin_amdgcn_mfma_f32_16x16x32_bf16(ah, bwv, acc2[mf], 0, 0, 0);
        }
    }

    if (r15 < NCLS) {
        float bias2 = b2[r15];
        #pragma unroll
        for (int mf = 0; mf < 2; ++mf) {
            int rbase = row0 + (wv << 5) + (mf << 4) + (khi << 2);
            #pragma unroll
            for (int q = 0; q < 4; ++q)
                out[(size_t)(rbase + q) * NCLS + r15] = acc2[mf][q] + bias2;
        }
    }
}

extern "C" void kernel_launch(void* const* d_in, const int* in_sizes, int n_in,
                              void* d_out, int out_size, void* d_ws, size_t ws_size,
                              hipStream_t stream) {
    const float* x      = (const float*)d_in[0];
    const float* conv_w = (const float*)d_in[1];
    const float* w1     = (const float*)d_in[2];
    const float* b1     = (const float*)d_in[3];
    const float* w2     = (const float*)d_in[4];
    const float* b2     = (const float*)d_in[5];
    float* out = (float*)d_out;

    unsigned short* w1b = (unsigned short*)d_ws;   // 128*800*2 = 204.8 KB
    unsigned short* w2b = w1b + 128 * KP;          // 16*128*2  = 4 KB

    build_weights<<<(128 * KP + 16 * 128 + 255) / 256, 256, 0, stream>>>(conv_w, w1, w2, w1b, w2b);
    fused_fwd<<<65536 / BM, 512, 0, stream>>>(x, w1b, b1, w2b, b2, out);
}

// Round 16
// 47.894 us; speedup vs baseline: 1.5088x; 1.0053x over previous
//
#include <hip/hip_runtime.h>

#define IMG 28
#define FLATK 784     // 28*28
#define OHW 26
#define FLAT 676      // 26*26
#define HID 100
#define NCLS 10
#define KP 800        // K padded to 25*32
#define BM 256        // rows per block (8 waves x 32 rows, mf=2)
#define BSTRIDE 808   // LDS B row stride in bf16 (800 + 8 pad)

typedef __attribute__((ext_vector_type(8))) short bfrag;   // 8 bf16 (4 VGPR)
typedef __attribute__((ext_vector_type(4))) float f32x4;
typedef __attribute__((ext_vector_type(4))) unsigned int u32x4;

__device__ __forceinline__ unsigned short f2bf(float f) {
    unsigned u = __float_as_uint(f);
    u = (u + 0x7fffu + ((u >> 16) & 1u)) >> 16;   // RNE
    return (unsigned short)u;
}

// Kernel 1: fold conv into fc1 -> bf16 W1eff [128 n][800 k] (zero-padded),
// and w2 -> bf16 [16 n][128 k] (zero-padded).
__global__ void build_weights(const float* __restrict__ conv_w,
                              const float* __restrict__ w1,
                              const float* __restrict__ w2,
                              unsigned short* __restrict__ w1b,
                              unsigned short* __restrict__ w2b) {
    int idx = blockIdx.x * blockDim.x + threadIdx.x;
    if (idx < 128 * KP) {
        int n = idx / KP, k = idx - n * KP;
        float val = 0.f;
        if (n < HID && k < FLATK) {
            int qr = k / IMG, qc = k % IMG;
            #pragma unroll
            for (int i = 0; i < 3; ++i) {
                int r = qr - i;
                if (r < 0 || r >= OHW) continue;
                #pragma unroll
                for (int j = 0; j < 3; ++j) {
                    int c = qc - j;
                    if (c < 0 || c >= OHW) continue;
                    val += conv_w[i * 3 + j] * w1[n * FLAT + r * OHW + c];
                }
            }
        }
        w1b[idx] = f2bf(val);
    } else {
        int t = idx - 128 * KP;
        if (t < 16 * 128) {
            int n = t >> 7, k = t & 127;
            float v = (n < NCLS && k < HID) ? w2[n * HID + k] : 0.f;
            w2b[t] = f2bf(v);
        }
    }
}

// load step S's A-fragments (both mf rows) into pre[PH]; PH,S literal ->
// SROA-promotes to registers (no scratch).
#define LOADA(PH, S) do {                                                      \
    int k_ = (S) * 32 + (khi << 3);                                            \
    if (k_ >= FLATK) k_ -= FLATK;  /* S=24 pad lanes: in-row garbage, B=0 */   \
    pre[PH][0] = *(const f32x4*)(xr0 + k_);                                    \
    pre[PH][1] = *(const f32x4*)(xr0 + k_ + 4);                                \
    pre[PH][2] = *(const f32x4*)(xr1 + k_);                                    \
    pre[PH][3] = *(const f32x4*)(xr1 + k_ + 4);                                \
} while (0)

// consume step S from pre[PH]: cvt_pk -> 2 A-fragments; 7 B ds_reads from
// LDS (lgkmcnt queue -- decoupled from the A vmcnt queue); 14 MFMA.
// Tile 6 overlaps cols 84..99 (avoids OOB LDS rows 100+).
#define COMP(PH, S) do {                                                       \
    union { u32x4 u; bfrag b; } a0_, a1_;                                      \
    asm("v_cvt_pk_bf16_f32 %0, %1, %2" : "=v"(a0_.u.x) : "v"(pre[PH][0].x), "v"(pre[PH][0].y)); \
    asm("v_cvt_pk_bf16_f32 %0, %1, %2" : "=v"(a0_.u.y) : "v"(pre[PH][0].z), "v"(pre[PH][0].w)); \
    asm("v_cvt_pk_bf16_f32 %0, %1, %2" : "=v"(a0_.u.z) : "v"(pre[PH][1].x), "v"(pre[PH][1].y)); \
    asm("v_cvt_pk_bf16_f32 %0, %1, %2" : "=v"(a0_.u.w) : "v"(pre[PH][1].z), "v"(pre[PH][1].w)); \
    asm("v_cvt_pk_bf16_f32 %0, %1, %2" : "=v"(a1_.u.x) : "v"(pre[PH][2].x), "v"(pre[PH][2].y)); \
    asm("v_cvt_pk_bf16_f32 %0, %1, %2" : "=v"(a1_.u.y) : "v"(pre[PH][2].z), "v"(pre[PH][2].w)); \
    asm("v_cvt_pk_bf16_f32 %0, %1, %2" : "=v"(a1_.u.z) : "v"(pre[PH][3].x), "v"(pre[PH][3].y)); \
    asm("v_cvt_pk_bf16_f32 %0, %1, %2" : "=v"(a1_.u.w) : "v"(pre[PH][3].z), "v"(pre[PH][3].w)); \
    _Pragma("unroll")                                                          \
    for (int nt = 0; nt < 7; ++nt) {                                           \
        int n_ = (nt < 6) ? ((nt << 4) + r15) : (84 + r15);                    \
        const bfrag bw = *(const bfrag*)(Blds + (size_t)n_ * BSTRIDE           \
                                         + (S) * 32 + (khi << 3));             \
        acc0[nt] = __builtin_amdgcn_mfma_f32_16x16x32_bf16(a0_.b, bw, acc0[nt], 0, 0, 0); \
        acc1[nt] = __builtin_amdgcn_mfma_f32_16x16x32_bf16(a1_.b, bw, acc1[nt], 0, 0, 0); \
    }                                                                          \
} while (0)

// Kernel 2: R14 template (B resident in LDS, barrier-free main loop, 8 waves
// x 32 rows, BM=256, grid=256 = 1 block/CU). Single change: A-prefetch ring
// depth 3 -> 5 (lookahead ~1000 cy >= HBM latency) -- discriminates
// latency-bound vs delivery-rate-bound for the x-stream.
__global__ __launch_bounds__(512) void fused_fwd(
    const float* __restrict__ x,              // [65536][784] f32
    const unsigned short* __restrict__ w1b,   // [128][800] bf16
    const float* __restrict__ b1,             // [100]
    const unsigned short* __restrict__ w2b,   // [16][128] bf16
    const float* __restrict__ b2,             // [10]
    float* __restrict__ out)                  // [65536][10] f32
{
    __shared__ char smem[100 * BSTRIDE * 2] __attribute__((aligned(128)));  // 161600 B
    unsigned short* Blds = (unsigned short*)smem;

    const int tid  = threadIdx.x;
    const int lane = tid & 63;
    const int wv   = tid >> 6;       // 0..7
    const int r15  = lane & 15;
    const int khi  = lane >> 4;      // 0..3 (k-slice *8)
    const int row0 = blockIdx.x * BM;

    // stage B: w1b rows 0..99 (incl. zero k-pad 784..799) -> LDS, 16B units
    for (int i = tid; i < 100 * 100; i += 512) {
        int n = i / 100, kv = i - n * 100;
        *(bfrag*)(Blds + (size_t)n * BSTRIDE + (kv << 3)) =
            *(const bfrag*)(w1b + (size_t)n * KP + (kv << 3));
    }
    __syncthreads();

    // A rows: lane holds row r15 of mf0 slab and row 16+r15 of mf1 slab
    const float* xr0 = x + (size_t)(row0 + (wv << 5) + r15) * FLATK;
    const float* xr1 = xr0 + 16 * FLATK;

    f32x4 acc0[7], acc1[7];
    #pragma unroll
    for (int n = 0; n < 7; ++n) {
        acc0[n] = f32x4{0.f, 0.f, 0.f, 0.f};
        acc1[n] = f32x4{0.f, 0.f, 0.f, 0.f};
    }

    f32x4 pre[5][4];   // depth-5 A ring (literal indices only)

    LOADA(0, 0); LOADA(1, 1); LOADA(2, 2); LOADA(3, 3); LOADA(4, 4);

    COMP(0, 0);  LOADA(0, 5);   COMP(1, 1);  LOADA(1, 6);
    COMP(2, 2);  LOADA(2, 7);   COMP(3, 3);  LOADA(3, 8);
    COMP(4, 4);  LOADA(4, 9);
    COMP(0, 5);  LOADA(0, 10);  COMP(1, 6);  LOADA(1, 11);
    COMP(2, 7);  LOADA(2, 12);  COMP(3, 8);  LOADA(3, 13);
    COMP(4, 9);  LOADA(4, 14);
    COMP(0, 10); LOADA(0, 15);  COMP(1, 11); LOADA(1, 16);
    COMP(2, 12); LOADA(2, 17);  COMP(3, 13); LOADA(3, 18);
    COMP(4, 14); LOADA(4, 19);
    COMP(0, 15); LOADA(0, 20);  COMP(1, 16); LOADA(1, 21);
    COMP(2, 17); LOADA(2, 22);  COMP(3, 18); LOADA(3, 23);
    COMP(4, 19); LOADA(4, 24);
    COMP(0, 20); COMP(1, 21);   COMP(2, 22); COMP(3, 23);
    COMP(4, 24);

    __syncthreads();   // B-LDS dead; alias H1 over it

    // epilogue 1: bias+relu -> bf16 h1 [256][136]; zero cols 100..127 (layer-2
    // k-range); nt0-5 write cols 0..95, nt6 writes cols 96..99 -- all disjoint.
    unsigned short (*H1)[136] = (unsigned short (*)[136])smem;
    for (int i = tid; i < 256 * 28; i += 512) {
        int r = i / 28, c = 100 + (i - (i / 28) * 28);
        H1[r][c] = 0;
    }
    #pragma unroll
    for (int nt = 0; nt < 7; ++nt) {
        int col = (nt < 6) ? ((nt << 4) + r15) : (84 + r15);
        bool wr = (nt < 6) || (col >= 96);
        float bias = (col < HID) ? b1[col] : 0.f;
        int rb0 = (wv << 5) + (khi << 2);
        if (wr) {
            #pragma unroll
            for (int q = 0; q < 4; ++q) {
                float v0 = acc0[nt][q] + bias;
                float v1 = acc1[nt][q] + bias;
                H1[rb0 + q][col]      = f2bf(fmaxf(v0, 0.f));
                H1[rb0 + 16 + q][col] = f2bf(fmaxf(v1, 0.f));
            }
        }
    }
    __syncthreads();

    // layer 2: 8 waves x 32 rows (mf=2) over K=128 (pads are exact zeros)
    f32x4 acc2[2] = {f32x4{0.f,0.f,0.f,0.f}, f32x4{0.f,0.f,0.f,0.f}};
    #pragma unroll
    for (int ks = 0; ks < 4; ++ks) {
        const bfrag bwv = *(const bfrag*)(w2b + r15 * 128 + (ks << 5) + (khi << 3));
        #pragma unroll
        for (int mf = 0; mf < 2; ++mf) {
            int r = (wv << 5) + (mf << 4) + r15;
            const bfrag ah = *(const bfrag*)&H1[r][(ks << 5) + (khi << 3)];
            acc2[mf] = __builtin_amdgcn_mfma_f32_16x16x32_bf16(ah, bwv, acc2[mf], 0, 0, 0);
        }
    }

    if (r15 < NCLS) {
        float bias2 = b2[r15];
        #pragma unroll
        for (int mf = 0; mf < 2; ++mf) {
            int rbase = row0 + (wv << 5) + (mf << 4) + (khi << 2);
            #pragma unroll
            for (int q = 0; q < 4; ++q)
                out[(size_t)(rbase + q) * NCLS + r15] = acc2[mf][q] + bias2;
        }
    }
}

extern "C" void kernel_launch(void* const* d_in, const int* in_sizes, int n_in,
                              void* d_out, int out_size, void* d_ws, size_t ws_size,
                              hipStream_t stream) {
    const float* x      = (const float*)d_in[0];
    const float* conv_w = (const float*)d_in[1];
    const float* w1     = (const float*)d_in[2];
    const float* b1     = (const float*)d_in[3];
    const float* w2     = (const float*)d_in[4];
    const float* b2     = (const float*)d_in[5];
    float* out = (float*)d_out;

    unsigned short* w1b = (unsigned short*)d_ws;   // 128*800*2 = 204.8 KB
    unsigned short* w2b = w1b + 128 * KP;          // 16*128*2  = 4 KB

    build_weights<<<(128 * KP + 16 * 128 + 255) / 256, 256, 0, stream>>>(conv_w, w1, w2, w1b, w2b);
    fused_fwd<<<65536 / BM, 512, 0, stream>>>(x, w1b, b1, w2b, b2, out);
}